// Round 1
// baseline (217.004 us; speedup 1.0000x reference)
//
#include <hip/hip_runtime.h>
#include <math.h>

// Problem constants (match reference: B,C,W,H,D = 2,256,32,32,32)
#define Bc   2
#define Cc   256
#define Nn   32768            // W*H*D
#define CHc  128              // C/2
#define LN_EPS 1e-5f

// Fused-kernel tiling
#define TN    64              // spatial positions per tile (block)
#define TPB   512             // threads per block (8 waves)
#define NQ    16              // n-quads per tile (TN/4)
#define CG    32              // channel groups
#define CPG   8               // channels per group (Cc/CG)
#define GRIDX (Nn / TN)       // 512 -> x Bc = 1024 blocks

// ---------------------------------------------------------------------------
// R7 gc_fused: one HBM pass over S and T — FOR REAL this time.
//
// R6 evidence: VGPR_Count=56 < 64-reg tile => the compiler REMATERIALIZED the
// 16 global loads for every round (3x L2/L3 re-read serialized behind 6
// barriers; VALUBusy 8.8%, latency-bound). __launch_bounds__ alone cannot
// forbid remat. Fixes:
//   (a) opaque-asm pin on every tile component after the mask FMAs: the asm
//       output is non-rematerializable, so rounds 1-3 MUST read registers.
//   (b) 6 barriers -> 2: three separate LDS partial buffers (52 KB; we are
//       2 blocks/CU by VGPR anyway, and 2x56.5 KB < 160 KB LDS) let all
//       three rounds write in one phase; one combined reduce phase splits
//       work over all 512 threads instead of 256 idling three times.
// Per-thread arithmetic (dot products, reduce orders, thread->atomic
// assignment) is unchanged => absmax must stay 0.0.
// UNSHIFTED softmax (shift-invariant; |mask| <~ 2, fp32-exact).
// ---------------------------------------------------------------------------
__global__ __launch_bounds__(TPB, 2) void gc_fused(
    const float* __restrict__ S, const float* __restrict__ T,
    const float* __restrict__ wms, const float* __restrict__ bms,
    const float* __restrict__ wmt, const float* __restrict__ bmt,
    float* __restrict__ ctxnum,   // [2][Bc][Cc] raw weighted sums
    float* __restrict__ rowsum,   // [Bc][Cc]
    float* __restrict__ den,      // [2][Bc] softmax denominators
    float* __restrict__ sumsq) {  // [1]
  const int b    = blockIdx.y;
  const int tid  = threadIdx.x;
  const int nq   = tid & (NQ - 1);
  const int cg   = tid >> 4;
  const int wv   = tid >> 6;
  const int lane = tid & 63;
  const int c0   = cg * CPG;
  const int n0   = blockIdx.x * TN + nq * 4;

  __shared__ float4 mredw[2][8][NQ];   // 4 KB   wave-level mask partials
  __shared__ float  creds[Cc * 17];    // 17 KB  ctx_s partials
  __shared__ float  credt[Cc * 17];    // 17 KB  ctx_t partials
  __shared__ float  credd[Cc * 17];    // 17 KB  rowsum partials
  __shared__ float  sqred[8];
  __shared__ float  denred[2][NQ];

  const float bS = bms[0];
  const float bT = bmt[0];

  const float* Sp = S + ((size_t)b * Cc + c0) * Nn + n0;
  const float* Tp = T + ((size_t)b * Cc + c0) * Nn + n0;

  // ---- issue all 16 independent tile loads up front ----
  float4 s4[CPG], t4[CPG];
#pragma unroll
  for (int i = 0; i < CPG; ++i) s4[i] = *(const float4*)(Sp + (size_t)i * Nn);
#pragma unroll
  for (int i = 0; i < CPG; ++i) t4[i] = *(const float4*)(Tp + (size_t)i * Nn);

  float wS[CPG], wT[CPG];
#pragma unroll
  for (int i = 0; i < CPG; ++i) { wS[i] = wms[c0 + i]; wT[i] = wmt[c0 + i]; }

  // ---- mask partials ----
  float4 ms = make_float4(0.f, 0.f, 0.f, 0.f);
  float4 mt = make_float4(0.f, 0.f, 0.f, 0.f);
#pragma unroll
  for (int i = 0; i < CPG; ++i) {
    ms.x += wS[i] * s4[i].x; ms.y += wS[i] * s4[i].y;
    ms.z += wS[i] * s4[i].z; ms.w += wS[i] * s4[i].w;
    mt.x += wT[i] * t4[i].x; mt.y += wT[i] * t4[i].y;
    mt.z += wT[i] * t4[i].z; mt.w += wT[i] * t4[i].w;
  }

  // ---- PIN the tile: opaque asm makes each value non-rematerializable, so
  // the post-barrier rounds reuse VGPRs instead of re-issuing global loads.
#pragma unroll
  for (int i = 0; i < CPG; ++i) {
    asm volatile("" : "+v"(s4[i].x), "+v"(s4[i].y), "+v"(s4[i].z),
                      "+v"(s4[i].w));
    asm volatile("" : "+v"(t4[i].x), "+v"(t4[i].y), "+v"(t4[i].z),
                      "+v"(t4[i].w));
  }

  // butterfly across the wave's 4 cg-subgroups (lane bits 4,5) — no barrier
#pragma unroll
  for (int m = 16; m <= 32; m <<= 1) {
    ms.x += __shfl_xor(ms.x, m); ms.y += __shfl_xor(ms.y, m);
    ms.z += __shfl_xor(ms.z, m); ms.w += __shfl_xor(ms.w, m);
    mt.x += __shfl_xor(mt.x, m); mt.y += __shfl_xor(mt.y, m);
    mt.z += __shfl_xor(mt.z, m); mt.w += __shfl_xor(mt.w, m);
  }
  if (lane < NQ) { mredw[0][wv][nq] = ms; mredw[1][wv][nq] = mt; }

  __syncthreads();   // barrier 1: mask partials visible

  // ---- assemble full mask, exponentiate ----
  float4 Ms = make_float4(0.f, 0.f, 0.f, 0.f);
  float4 Mt = make_float4(0.f, 0.f, 0.f, 0.f);
#pragma unroll
  for (int w = 0; w < 8; ++w) {
    const float4 a = mredw[0][w][nq];
    Ms.x += a.x; Ms.y += a.y; Ms.z += a.z; Ms.w += a.w;
    const float4 c = mredw[1][w][nq];
    Mt.x += c.x; Mt.y += c.y; Mt.z += c.z; Mt.w += c.w;
  }
  float4 es, et;
  es.x = __expf(Ms.x + bS); es.y = __expf(Ms.y + bS);
  es.z = __expf(Ms.z + bS); es.w = __expf(Ms.w + bS);
  et.x = __expf(Mt.x + bT); et.y = __expf(Mt.y + bT);
  et.z = __expf(Mt.z + bT); et.w = __expf(Mt.w + bT);

  if (tid < NQ) {  // cg==0 threads: one denominator contribution per nq
    denred[0][tid] = es.x + es.y + es.z + es.w;
    denred[1][tid] = et.x + et.y + et.z + et.w;
  }

  // ---- all three partial sets written from the register-resident tile ----
#pragma unroll
  for (int i = 0; i < CPG; ++i)
    creds[(c0 + i) * 17 + nq] =
        s4[i].x * es.x + s4[i].y * es.y + s4[i].z * es.z + s4[i].w * es.w;
#pragma unroll
  for (int i = 0; i < CPG; ++i)
    credt[(c0 + i) * 17 + nq] =
        t4[i].x * et.x + t4[i].y * et.y + t4[i].z * et.z + t4[i].w * et.w;

  float sq = 0.f;
#pragma unroll
  for (int i = 0; i < CPG; ++i) {
    const float dx = s4[i].x - t4[i].x, dy = s4[i].y - t4[i].y;
    const float dz = s4[i].z - t4[i].z, dw = s4[i].w - t4[i].w;
    credd[(c0 + i) * 17 + nq] = dx + dy + dz + dw;
    sq += dx * dx + dy * dy + dz * dz + dw * dw;
  }
#pragma unroll
  for (int m = 1; m < 64; m <<= 1) sq += __shfl_xor(sq, m);
  if (lane == 0) sqred[wv] = sq;

  __syncthreads();   // barrier 2: all partials visible

  // ---- combined reduce + atomics, balanced across all 512 threads ----
  if (tid < Cc) {
    float a = 0.f, r = 0.f;
#pragma unroll
    for (int k = 0; k < NQ; ++k) a += creds[tid * 17 + k];
#pragma unroll
    for (int k = 0; k < NQ; ++k) r += credd[tid * 17 + k];
    atomicAdd(&ctxnum[((size_t)0 * Bc + b) * Cc + tid], a);
    atomicAdd(&rowsum[(size_t)b * Cc + tid], r);
  } else {
    const int c = tid - Cc;
    float t = 0.f;
#pragma unroll
    for (int k = 0; k < NQ; ++k) t += credt[c * 17 + k];
    atomicAdd(&ctxnum[((size_t)1 * Bc + b) * Cc + c], t);
    if (tid == Cc) {           // same thread id & order as R6 -> bit-exact
      float v = 0.f;
#pragma unroll
      for (int w = 0; w < 8; ++w) v += sqred[w];
      atomicAdd(sumsq, v);
    } else if (tid == Cc + 1) {
      float a = 0.f, cden = 0.f;
#pragma unroll
      for (int k = 0; k < NQ; ++k) { a += denred[0][k]; cden += denred[1][k]; }
      atomicAdd(&den[0 * Bc + b], a);
      atomicAdd(&den[1 * Bc + b], cden);
    }
  }
}

// ---------------------------------------------------------------------------
// R7 K4: channel_add MLP per (tt,b) (grid 4, block 1024) with the final
// scalar folded in via the last-block-done pattern (device fence + atomic
// bump). Saves the k4b launch and its global round-trip.
// ---------------------------------------------------------------------------
__global__ __launch_bounds__(1024) void gc_k4_mlp_final(
    const float* __restrict__ ctxr, const float* __restrict__ den,
    const float* __restrict__ w1s, const float* __restrict__ b1s,
    const float* __restrict__ gs,  const float* __restrict__ bes,
    const float* __restrict__ w2s, const float* __restrict__ b2s,
    const float* __restrict__ w1t, const float* __restrict__ b1t,
    const float* __restrict__ gt,  const float* __restrict__ bet,
    const float* __restrict__ w2t, const float* __restrict__ b2t,
    const float* __restrict__ rowsum, const float* __restrict__ sumsq,
    float* __restrict__ addv, unsigned int* __restrict__ bump,
    float* __restrict__ out) {
  const int tt  = blockIdx.x >> 1;
  const int b   = blockIdx.x & 1;
  const int tid = threadIdx.x;

  const float* w1 = tt ? w1t : w1s;
  const float* b1 = tt ? b1t : b1s;
  const float* g  = tt ? gt  : gs;
  const float* be = tt ? bet : bes;
  const float* w2 = tt ? w2t : w2s;
  const float* b2 = tt ? b2t : b2s;

  __shared__ float cxs[Cc];
  __shared__ float part[1024];
  __shared__ float hbuf[CHc];
  __shared__ float hr[CHc];
  __shared__ float2 red2[128];
  __shared__ float mu_s, rstd_s;
  __shared__ unsigned int lastv;
  __shared__ float red[256];

  if (tid < Cc)
    cxs[tid] = ctxr[((size_t)tt * Bc + b) * Cc + tid] / den[tt * Bc + b];
  __syncthreads();

  // stage 1: h[j] = sum_c ctx[c]*w1[j][c] + b1[j]   (128 j x 8 segments)
  {
    const int j = tid >> 3, s = tid & 7;
    const float* wr = w1 + j * Cc + s * 32;
    const float4* cx4 = (const float4*)(cxs + s * 32);
    float acc = 0.f;
#pragma unroll
    for (int k = 0; k < 8; ++k) {
      const float4 w = *(const float4*)(wr + k * 4);
      const float4 x = cx4[k];
      acc += w.x * x.x + w.y * x.y + w.z * x.z + w.w * x.w;
    }
    part[tid] = acc;
  }
  __syncthreads();
  if (tid < CHc) {
    float h = b1[tid];
#pragma unroll
    for (int q = 0; q < 8; ++q) h += part[tid * 8 + q];
    hbuf[tid] = h;
  }
  __syncthreads();

  // LN stats over 128
  if (tid < CHc) {
    const float v = hbuf[tid];
    red2[tid] = make_float2(v, v * v);
  }
  __syncthreads();
  for (int s = 64; s > 0; s >>= 1) {
    if (tid < s) {
      red2[tid].x += red2[tid + s].x;
      red2[tid].y += red2[tid + s].y;
    }
    __syncthreads();
  }
  if (tid == 0) {
    const float mu = red2[0].x / (float)CHc;
    const float var = red2[0].y / (float)CHc - mu * mu;
    mu_s = mu;
    rstd_s = rsqrtf(var + LN_EPS);
  }
  __syncthreads();
  if (tid < CHc) {
    const float v = (hbuf[tid] - mu_s) * rstd_s * g[tid] + be[tid];
    hr[tid] = v > 0.f ? v : 0.f;
  }
  __syncthreads();

  // stage 3: addv[c] = sum_j hr[j]*w2[c][j] + b2[c]   (256 c x 4 segments)
  {
    const int c = tid >> 2, q = tid & 3;
    const float* wr = w2 + c * CHc + q * 32;
    const float4* h4 = (const float4*)(hr + q * 32);
    float acc = 0.f;
#pragma unroll
    for (int k = 0; k < 8; ++k) {
      const float4 w = *(const float4*)(wr + k * 4);
      const float4 x = h4[k];
      acc += w.x * x.x + w.y * x.y + w.z * x.z + w.w * x.w;
    }
    part[tid] = acc;
  }
  __syncthreads();
  if (tid < Cc) {
    float acc = b2[tid];
#pragma unroll
    for (int q = 0; q < 4; ++q) acc += part[tid * 4 + q];
    addv[((size_t)tt * Bc + b) * Cc + tid] = acc;
  }

  // ---- last-block-done: fold in the final scalar reduction ----
  __threadfence();            // push this block's addv to device scope
  __syncthreads();            // all stores above are fenced
  if (tid == 0) lastv = atomicAdd(bump, 1u);
  __syncthreads();
  if (lastv == 3u) {          // we are the last of the 4 blocks
    __threadfence();          // invalidate caches: see the other blocks' addv
    float p = 0.f;
    if (tid < 256) {
      for (int job = tid; job < Bc * Cc; job += 256) {
        const int c = job & (Cc - 1);
        const int bb = job >> 8;
        const float delta = addv[((size_t)0 * Bc + bb) * Cc + c] -
                            addv[((size_t)1 * Bc + bb) * Cc + c];
        p += 2.f * delta * rowsum[(size_t)bb * Cc + c] +
             (float)Nn * delta * delta;
      }
      red[tid] = p;
    }
    __syncthreads();
    for (int s = 128; s > 0; s >>= 1) {
      if (tid < s) red[tid] += red[tid + s];
      __syncthreads();
    }
    if (tid == 0) out[0] = (red[0] + sumsq[0]) / (float)Bc;
  }
}

// ---------------------------------------------------------------------------
extern "C" void kernel_launch(void* const* d_in, const int* in_sizes, int n_in,
                              void* d_out, int out_size, void* d_ws,
                              size_t ws_size, hipStream_t stream) {
  const float* S   = (const float*)d_in[0];
  const float* T   = (const float*)d_in[1];
  const float* wms = (const float*)d_in[2];
  const float* bms = (const float*)d_in[3];
  const float* wmt = (const float*)d_in[4];
  const float* bmt = (const float*)d_in[5];
  const float* w1s = (const float*)d_in[6];
  const float* b1s = (const float*)d_in[7];
  const float* gs  = (const float*)d_in[8];
  const float* bes = (const float*)d_in[9];
  const float* w2s = (const float*)d_in[10];
  const float* b2s = (const float*)d_in[11];
  const float* w1t = (const float*)d_in[12];
  const float* b1t = (const float*)d_in[13];
  const float* gt  = (const float*)d_in[14];
  const float* bet = (const float*)d_in[15];
  const float* w2t = (const float*)d_in[16];
  const float* b2t = (const float*)d_in[17];
  float* out = (float*)d_out;

  // ws layout (floats) — accumulators + bump first so one memset zeroes all.
  float* ws     = (float*)d_ws;
  float* ctxnum = ws;                         // 2*B*C = 1024
  float* rowsum = ctxnum + 2 * Bc * Cc;       // B*C   = 512
  float* den    = rowsum + Bc * Cc;           // 4
  float* sumsq  = den + 4;                    // 1
  unsigned int* bump = (unsigned int*)(sumsq + 1);  // 1
  float* addv   = (float*)(bump + 1);         // 2*B*C = 1024

  hipMemsetAsync(d_ws, 0,
                 (2 * Bc * Cc + Bc * Cc + 4 + 1 + 1) * sizeof(float), stream);

  gc_fused<<<dim3(GRIDX, Bc), TPB, 0, stream>>>(S, T, wms, bms, wmt, bmt,
                                                ctxnum, rowsum, den, sumsq);
  gc_k4_mlp_final<<<4, 1024, 0, stream>>>(ctxnum, den, w1s, b1s, gs, bes,
                                          w2s, b2s, w1t, b1t, gt, bet,
                                          w2t, b2t, rowsum, sumsq, addv,
                                          bump, out);
}

// Round 2
// 195.836 us; speedup vs baseline: 1.1081x; 1.1081x over previous
//
#include <hip/hip_runtime.h>
#include <math.h>

// Problem constants (match reference: B,C,W,H,D = 2,256,32,32,32)
#define Bc   2
#define Cc   256
#define Nn   32768            // W*H*D
#define CHc  128              // C/2
#define LN_EPS 1e-5f

// Fused-kernel tiling
#define TN    64              // spatial positions per tile (block)
#define TPB   512             // threads per block (8 waves)
#define NQ    16              // n-quads per tile (TN/4)
#define CG    32              // channel groups
#define CPG   8               // channels per group (Cc/CG)
#define GRIDX (Nn / TN)       // 512 -> x Bc = 1024 blocks
#define NSLOT 16              // atomic-contention slots

// ---------------------------------------------------------------------------
// R8 gc_fused: R6 body (remat tile, single cred buffer, 22 KB LDS) + SLOTTED
// accumulators.
//
// R5/R6/R7 invariance (~56-59 us across wildly different inner structures)
// points at the shared tail: ~770 atomicAdds per block into the SAME 1536
// floats (48 cachelines). Per line: 32 lanes x 512 blocks = 16K serialized
// L2-bank RMWs (~10-15 us of serial work), and waves cannot retire until
// their atomics land (vmcnt drain at endpgm) -> block slots not freed ->
// ~4 serialized dispatch rounds. slot = blockIdx.x & 15 gives 16 independent
// partial arrays: per-line RMWs drop 16384 -> 1024 (sub-us). k4a/k4b fold
// the slots at load time.
// R7's last-block-done merge REGRESSED ~9 us (device-scope fences) -> revert
// to separate k4a/k4b. R7's pin was neutral -> dropped (remat re-reads are
// L2/L3-served per FETCH_SIZE).
// UNSHIFTED softmax (shift-invariant; |mask| <~ 2, fp32-exact).
// ---------------------------------------------------------------------------
__global__ __launch_bounds__(TPB, 2) void gc_fused(
    const float* __restrict__ S, const float* __restrict__ T,
    const float* __restrict__ wms, const float* __restrict__ bms,
    const float* __restrict__ wmt, const float* __restrict__ bmt,
    float* __restrict__ ctxnum,   // [NSLOT][2][Bc][Cc] raw weighted sums
    float* __restrict__ rowsum,   // [NSLOT][Bc][Cc]
    float* __restrict__ den,      // [NSLOT][4] softmax denominators (tt*2+b)
    float* __restrict__ sumsq) {  // [NSLOT]
  const int b    = blockIdx.y;
  const int tid  = threadIdx.x;
  const int nq   = tid & (NQ - 1);
  const int cg   = tid >> 4;
  const int wv   = tid >> 6;
  const int lane = tid & 63;
  const int c0   = cg * CPG;
  const int n0   = blockIdx.x * TN + nq * 4;
  const int slot = blockIdx.x & (NSLOT - 1);

  __shared__ float4 mredw[2][8][NQ];   // 4 KB   wave-level mask partials
  __shared__ float  cred[Cc * 17];     // 17 KB  reused channel-partial buffer
  __shared__ float  sqred[8];
  __shared__ float  denred[2][NQ];

  const float bS = bms[0];
  const float bT = bmt[0];

  const float* Sp = S + ((size_t)b * Cc + c0) * Nn + n0;
  const float* Tp = T + ((size_t)b * Cc + c0) * Nn + n0;

  // ---- issue all 16 independent tile loads up front ----
  float4 s4[CPG], t4[CPG];
#pragma unroll
  for (int i = 0; i < CPG; ++i) s4[i] = *(const float4*)(Sp + (size_t)i * Nn);
#pragma unroll
  for (int i = 0; i < CPG; ++i) t4[i] = *(const float4*)(Tp + (size_t)i * Nn);

  float wS[CPG], wT[CPG];
#pragma unroll
  for (int i = 0; i < CPG; ++i) { wS[i] = wms[c0 + i]; wT[i] = wmt[c0 + i]; }

  // ---- mask partials (only ms/mt accumulators live besides the tile) ----
  float4 ms = make_float4(0.f, 0.f, 0.f, 0.f);
  float4 mt = make_float4(0.f, 0.f, 0.f, 0.f);
#pragma unroll
  for (int i = 0; i < CPG; ++i) {
    ms.x += wS[i] * s4[i].x; ms.y += wS[i] * s4[i].y;
    ms.z += wS[i] * s4[i].z; ms.w += wS[i] * s4[i].w;
    mt.x += wT[i] * t4[i].x; mt.y += wT[i] * t4[i].y;
    mt.z += wT[i] * t4[i].z; mt.w += wT[i] * t4[i].w;
  }

  // butterfly across the wave's 4 cg-subgroups (lane bits 4,5) — no barrier
#pragma unroll
  for (int m = 16; m <= 32; m <<= 1) {
    ms.x += __shfl_xor(ms.x, m); ms.y += __shfl_xor(ms.y, m);
    ms.z += __shfl_xor(ms.z, m); ms.w += __shfl_xor(ms.w, m);
    mt.x += __shfl_xor(mt.x, m); mt.y += __shfl_xor(mt.y, m);
    mt.z += __shfl_xor(mt.z, m); mt.w += __shfl_xor(mt.w, m);
  }
  if (lane < NQ) { mredw[0][wv][nq] = ms; mredw[1][wv][nq] = mt; }

  __syncthreads();   // barrier 1: mask partials visible

  float4 Ms = make_float4(0.f, 0.f, 0.f, 0.f);
  float4 Mt = make_float4(0.f, 0.f, 0.f, 0.f);
#pragma unroll
  for (int w = 0; w < 8; ++w) {
    const float4 a = mredw[0][w][nq];
    Ms.x += a.x; Ms.y += a.y; Ms.z += a.z; Ms.w += a.w;
    const float4 c = mredw[1][w][nq];
    Mt.x += c.x; Mt.y += c.y; Mt.z += c.z; Mt.w += c.w;
  }
  float4 es, et;
  es.x = __expf(Ms.x + bS); es.y = __expf(Ms.y + bS);
  es.z = __expf(Ms.z + bS); es.w = __expf(Ms.w + bS);
  et.x = __expf(Mt.x + bT); et.y = __expf(Mt.y + bT);
  et.z = __expf(Mt.z + bT); et.w = __expf(Mt.w + bT);

  if (tid < NQ) {  // cg==0 threads: one denominator contribution per nq
    denred[0][tid] = es.x + es.y + es.z + es.w;
    denred[1][tid] = et.x + et.y + et.z + et.w;
  }

  // ---- round 1: ctx_s channel partials ----
#pragma unroll
  for (int i = 0; i < CPG; ++i)
    cred[(c0 + i) * 17 + nq] =
        s4[i].x * es.x + s4[i].y * es.y + s4[i].z * es.z + s4[i].w * es.w;
  __syncthreads();   // barrier 2
  if (tid < Cc) {
    float a = 0.f;
#pragma unroll
    for (int k = 0; k < NQ; ++k) a += cred[tid * 17 + k];
    atomicAdd(&ctxnum[(((size_t)slot * 2 + 0) * Bc + b) * Cc + tid], a);
  } else if (tid == Cc + 1) {
    float a = 0.f, c = 0.f;
#pragma unroll
    for (int k = 0; k < NQ; ++k) { a += denred[0][k]; c += denred[1][k]; }
    atomicAdd(&den[slot * 4 + 0 * Bc + b], a);
    atomicAdd(&den[slot * 4 + 1 * Bc + b], c);
  }
  __syncthreads();   // barrier 3 (cred write-after-read guard)

  // ---- round 2: ctx_t channel partials ----
#pragma unroll
  for (int i = 0; i < CPG; ++i)
    cred[(c0 + i) * 17 + nq] =
        t4[i].x * et.x + t4[i].y * et.y + t4[i].z * et.z + t4[i].w * et.w;
  __syncthreads();   // barrier 4
  if (tid < Cc) {
    float c = 0.f;
#pragma unroll
    for (int k = 0; k < NQ; ++k) c += cred[tid * 17 + k];
    atomicAdd(&ctxnum[(((size_t)slot * 2 + 1) * Bc + b) * Cc + tid], c);
  }
  __syncthreads();   // barrier 5

  // ---- round 3: rowsum partials + sumsq (recomputed from s4/t4) ----
  float sq = 0.f;
#pragma unroll
  for (int i = 0; i < CPG; ++i) {
    const float dx = s4[i].x - t4[i].x, dy = s4[i].y - t4[i].y;
    const float dz = s4[i].z - t4[i].z, dw = s4[i].w - t4[i].w;
    cred[(c0 + i) * 17 + nq] = dx + dy + dz + dw;
    sq += dx * dx + dy * dy + dz * dz + dw * dw;
  }
#pragma unroll
  for (int m = 1; m < 64; m <<= 1) sq += __shfl_xor(sq, m);
  if (lane == 0) sqred[wv] = sq;
  __syncthreads();   // barrier 6
  if (tid < Cc) {
    float r = 0.f;
#pragma unroll
    for (int k = 0; k < NQ; ++k) r += cred[tid * 17 + k];
    atomicAdd(&rowsum[((size_t)slot * Bc + b) * Cc + tid], r);
  } else if (tid == Cc) {
    float v = 0.f;
#pragma unroll
    for (int w = 0; w < 8; ++w) v += sqred[w];
    atomicAdd(&sumsq[slot], v);
  }
}

// ---------------------------------------------------------------------------
// K4a: channel_add MLP per (tt,b). grid 4, block 1024. ctx = fold 16 slots of
// ctxnum / fold 16 slots of den at load time. float4 weight loads.
// ---------------------------------------------------------------------------
__global__ __launch_bounds__(1024) void gc_k4a_mlp(
    const float* __restrict__ ctxr, const float* __restrict__ den,
    const float* __restrict__ w1s, const float* __restrict__ b1s,
    const float* __restrict__ gs,  const float* __restrict__ bes,
    const float* __restrict__ w2s, const float* __restrict__ b2s,
    const float* __restrict__ w1t, const float* __restrict__ b1t,
    const float* __restrict__ gt,  const float* __restrict__ bet,
    const float* __restrict__ w2t, const float* __restrict__ b2t,
    float* __restrict__ addv) {
  const int tt  = blockIdx.x >> 1;
  const int b   = blockIdx.x & 1;
  const int tid = threadIdx.x;

  const float* w1 = tt ? w1t : w1s;
  const float* b1 = tt ? b1t : b1s;
  const float* g  = tt ? gt  : gs;
  const float* be = tt ? bet : bes;
  const float* w2 = tt ? w2t : w2s;
  const float* b2 = tt ? b2t : b2s;

  __shared__ float cxs[Cc];
  __shared__ float part[1024];
  __shared__ float hbuf[CHc];
  __shared__ float hr[CHc];
  __shared__ float2 red2[128];
  __shared__ float mu_s, rstd_s;

  if (tid < Cc) {
    float num = 0.f, dn = 0.f;
#pragma unroll
    for (int k = 0; k < NSLOT; ++k) {
      num += ctxr[(((size_t)k * 2 + tt) * Bc + b) * Cc + tid];
      dn  += den[k * 4 + tt * Bc + b];
    }
    cxs[tid] = num / dn;
  }
  __syncthreads();

  // stage 1: h[j] = sum_c ctx[c]*w1[j][c] + b1[j]   (128 j x 8 segments)
  {
    const int j = tid >> 3, s = tid & 7;
    const float* wr = w1 + j * Cc + s * 32;
    const float4* cx4 = (const float4*)(cxs + s * 32);
    float acc = 0.f;
#pragma unroll
    for (int k = 0; k < 8; ++k) {
      const float4 w = *(const float4*)(wr + k * 4);
      const float4 x = cx4[k];
      acc += w.x * x.x + w.y * x.y + w.z * x.z + w.w * x.w;
    }
    part[tid] = acc;
  }
  __syncthreads();
  if (tid < CHc) {
    float h = b1[tid];
#pragma unroll
    for (int q = 0; q < 8; ++q) h += part[tid * 8 + q];
    hbuf[tid] = h;
  }
  __syncthreads();

  // LN stats over 128
  if (tid < CHc) {
    const float v = hbuf[tid];
    red2[tid] = make_float2(v, v * v);
  }
  __syncthreads();
  for (int s = 64; s > 0; s >>= 1) {
    if (tid < s) {
      red2[tid].x += red2[tid + s].x;
      red2[tid].y += red2[tid + s].y;
    }
    __syncthreads();
  }
  if (tid == 0) {
    const float mu = red2[0].x / (float)CHc;
    const float var = red2[0].y / (float)CHc - mu * mu;
    mu_s = mu;
    rstd_s = rsqrtf(var + LN_EPS);
  }
  __syncthreads();
  if (tid < CHc) {
    const float v = (hbuf[tid] - mu_s) * rstd_s * g[tid] + be[tid];
    hr[tid] = v > 0.f ? v : 0.f;
  }
  __syncthreads();

  // stage 3: addv[c] = sum_j hr[j]*w2[c][j] + b2[c]   (256 c x 4 segments)
  {
    const int c = tid >> 2, q = tid & 3;
    const float* wr = w2 + c * CHc + q * 32;
    const float4* h4 = (const float4*)(hr + q * 32);
    float acc = 0.f;
#pragma unroll
    for (int k = 0; k < 8; ++k) {
      const float4 w = *(const float4*)(wr + k * 4);
      const float4 x = h4[k];
      acc += w.x * x.x + w.y * x.y + w.z * x.z + w.w * x.w;
    }
    part[tid] = acc;
  }
  __syncthreads();
  if (tid < Cc) {
    float acc = b2[tid];
#pragma unroll
    for (int q = 0; q < 4; ++q) acc += part[tid * 4 + q];
    addv[((size_t)tt * Bc + b) * Cc + tid] = acc;
  }
}

// ---------------------------------------------------------------------------
// K4b: final scalar. 1 block, 256 thr. Folds the 16 rowsum/sumsq slots.
// out = (sumsq + sum_{b,c} [2*delta*rowsum + N*delta^2]) / B
// ---------------------------------------------------------------------------
__global__ __launch_bounds__(256) void gc_k4b_final(
    const float* __restrict__ addv, const float* __restrict__ rowsum,
    const float* __restrict__ sumsq, float* __restrict__ out) {
  const int tid = threadIdx.x;
  __shared__ float red[256];
  float part = 0.f;
  for (int job = tid; job < Bc * Cc; job += 256) {
    const int c = job & (Cc - 1);
    const int b = job >> 8;
    const float delta = addv[((size_t)0 * Bc + b) * Cc + c] -
                        addv[((size_t)1 * Bc + b) * Cc + c];
    float rs = 0.f;
#pragma unroll
    for (int k = 0; k < NSLOT; ++k)
      rs += rowsum[((size_t)k * Bc + b) * Cc + c];
    part += 2.f * delta * rs + (float)Nn * delta * delta;
  }
  red[tid] = part;
  __syncthreads();
  for (int s = 128; s > 0; s >>= 1) {
    if (tid < s) red[tid] += red[tid + s];
    __syncthreads();
  }
  if (tid == 0) {
    float sq = 0.f;
#pragma unroll
    for (int k = 0; k < NSLOT; ++k) sq += sumsq[k];
    out[0] = (red[0] + sq) / (float)Bc;
  }
}

// ---------------------------------------------------------------------------
extern "C" void kernel_launch(void* const* d_in, const int* in_sizes, int n_in,
                              void* d_out, int out_size, void* d_ws,
                              size_t ws_size, hipStream_t stream) {
  const float* S   = (const float*)d_in[0];
  const float* T   = (const float*)d_in[1];
  const float* wms = (const float*)d_in[2];
  const float* bms = (const float*)d_in[3];
  const float* wmt = (const float*)d_in[4];
  const float* bmt = (const float*)d_in[5];
  const float* w1s = (const float*)d_in[6];
  const float* b1s = (const float*)d_in[7];
  const float* gs  = (const float*)d_in[8];
  const float* bes = (const float*)d_in[9];
  const float* w2s = (const float*)d_in[10];
  const float* b2s = (const float*)d_in[11];
  const float* w1t = (const float*)d_in[12];
  const float* b1t = (const float*)d_in[13];
  const float* gt  = (const float*)d_in[14];
  const float* bet = (const float*)d_in[15];
  const float* w2t = (const float*)d_in[16];
  const float* b2t = (const float*)d_in[17];
  float* out = (float*)d_out;

  // ws layout (floats) — slotted accumulators first; one memset zeroes all.
  float* ws     = (float*)d_ws;
  float* ctxnum = ws;                               // NSLOT*2*B*C = 16384
  float* rowsum = ctxnum + NSLOT * 2 * Bc * Cc;     // NSLOT*B*C   = 8192
  float* den    = rowsum + NSLOT * Bc * Cc;         // NSLOT*4     = 64
  float* sumsq  = den + NSLOT * 4;                  // NSLOT       = 16
  float* addv   = sumsq + NSLOT;                    // 2*B*C       = 1024

  hipMemsetAsync(d_ws, 0,
                 (NSLOT * (2 * Bc * Cc + Bc * Cc + 4 + 1)) * sizeof(float),
                 stream);

  gc_fused<<<dim3(GRIDX, Bc), TPB, 0, stream>>>(S, T, wms, bms, wmt, bmt,
                                                ctxnum, rowsum, den, sumsq);
  gc_k4a_mlp<<<4, 1024, 0, stream>>>(ctxnum, den, w1s, b1s, gs, bes, w2s, b2s,
                                     w1t, b1t, gt, bet, w2t, b2t, addv);
  gc_k4b_final<<<1, 256, 0, stream>>>(addv, rowsum, sumsq, out);
}

// Round 3
// 192.562 us; speedup vs baseline: 1.1269x; 1.0170x over previous
//
#include <hip/hip_runtime.h>
#include <math.h>

// Problem constants (match reference: B,C,W,H,D = 2,256,32,32,32)
#define Bc   2
#define Cc   256
#define Nn   32768            // W*H*D
#define CHc  128              // C/2
#define LN_EPS 1e-5f

// Fused-kernel tiling
#define TN    64              // spatial positions per tile (block)
#define TPB   512             // threads per block (8 waves)
#define NQ    16              // n-quads per tile (TN/4)
#define CG    32              // channel groups
#define CPG   8               // channels per group (Cc/CG)
#define GRIDX (Nn / TN)       // 512 -> x Bc = 1024 blocks
#define NSLOT 32              // atomic-contention slots

// ---------------------------------------------------------------------------
// R9 gc_fused: barrier chain (6) -> ONE barrier; cred LDS -> in-wave
// butterfly reductions.
//
// R8 evidence: slotting the atomics bought -11 us (contention theory
// confirmed). Remaining gap to the ~25-30 us blended HBM+L3 floor is the
// serialization structure: 5 post-mask barriers chaining all 8 waves, with
// only 256/512 threads active in each cred read phase.
// KEY OBSERVATION: threads sharing a channel group (same cg, all 16 nq) are
// 16 CONSECUTIVE LANES of one wave -> per-channel spatial reduction is a
// 4-step __shfl_xor butterfly over lane bits 0-3, no LDS, no barrier.
// The diff/sumsq round depends only on s4/t4 (not softmax) -> runs BEFORE
// the mask barrier. The softmax denominator falls out of the same butterfly.
// LDS 22 KB -> 4.3 KB; barriers 6 -> 1; NSLOT 16 -> 32.
// All register arrays statically indexed (unrolled select chain, rule #20).
// UNSHIFTED softmax (shift-invariant; |mask| <~ 2, fp32-exact).
// ---------------------------------------------------------------------------
__global__ __launch_bounds__(TPB, 2) void gc_fused(
    const float* __restrict__ S, const float* __restrict__ T,
    const float* __restrict__ wms, const float* __restrict__ bms,
    const float* __restrict__ wmt, const float* __restrict__ bmt,
    float* __restrict__ ctxnum,   // [NSLOT][2][Bc][Cc] raw weighted sums
    float* __restrict__ rowsum,   // [NSLOT][Bc][Cc]
    float* __restrict__ den,      // [NSLOT][4] softmax denominators
    float* __restrict__ sumsq) {  // [NSLOT]
  const int b    = blockIdx.y;
  const int tid  = threadIdx.x;
  const int nq   = tid & (NQ - 1);
  const int cg   = tid >> 4;
  const int wv   = tid >> 6;
  const int lane = tid & 63;
  const int sub  = lane & 15;          // position within 16-lane subgroup
  const int c0   = cg * CPG;
  const int n0   = blockIdx.x * TN + nq * 4;
  const int slot = blockIdx.x & (NSLOT - 1);

  __shared__ float4 mredw[2][8][NQ];   // 4 KB  wave-level mask partials
  __shared__ float  sqred[8];

  const float bS = bms[0];
  const float bT = bmt[0];

  const float* Sp = S + ((size_t)b * Cc + c0) * Nn + n0;
  const float* Tp = T + ((size_t)b * Cc + c0) * Nn + n0;

  // ---- issue all 16 independent tile loads up front ----
  float4 s4[CPG], t4[CPG];
#pragma unroll
  for (int i = 0; i < CPG; ++i) s4[i] = *(const float4*)(Sp + (size_t)i * Nn);
#pragma unroll
  for (int i = 0; i < CPG; ++i) t4[i] = *(const float4*)(Tp + (size_t)i * Nn);

  float wS[CPG], wT[CPG];
#pragma unroll
  for (int i = 0; i < CPG; ++i) { wS[i] = wms[c0 + i]; wT[i] = wmt[c0 + i]; }

  // ---- mask partials ----
  float4 ms = make_float4(0.f, 0.f, 0.f, 0.f);
  float4 mt = make_float4(0.f, 0.f, 0.f, 0.f);
#pragma unroll
  for (int i = 0; i < CPG; ++i) {
    ms.x += wS[i] * s4[i].x; ms.y += wS[i] * s4[i].y;
    ms.z += wS[i] * s4[i].z; ms.w += wS[i] * s4[i].w;
    mt.x += wT[i] * t4[i].x; mt.y += wT[i] * t4[i].y;
    mt.z += wT[i] * t4[i].z; mt.w += wT[i] * t4[i].w;
  }

  // butterfly across the wave's 4 cg-subgroups (lane bits 4,5) — no barrier
#pragma unroll
  for (int m = 16; m <= 32; m <<= 1) {
    ms.x += __shfl_xor(ms.x, m); ms.y += __shfl_xor(ms.y, m);
    ms.z += __shfl_xor(ms.z, m); ms.w += __shfl_xor(ms.w, m);
    mt.x += __shfl_xor(mt.x, m); mt.y += __shfl_xor(mt.y, m);
    mt.z += __shfl_xor(mt.z, m); mt.w += __shfl_xor(mt.w, m);
  }
  if (lane < NQ) { mredw[0][wv][nq] = ms; mredw[1][wv][nq] = mt; }

  // ---- pre-barrier: diff partials + sumsq (independent of softmax) ----
  float pd[CPG];
  float sq = 0.f;
#pragma unroll
  for (int i = 0; i < CPG; ++i) {
    const float dx = s4[i].x - t4[i].x, dy = s4[i].y - t4[i].y;
    const float dz = s4[i].z - t4[i].z, dw = s4[i].w - t4[i].w;
    pd[i] = dx + dy + dz + dw;
    sq += dx * dx + dy * dy + dz * dz + dw * dw;
  }
#pragma unroll
  for (int m = 1; m <= 8; m <<= 1) {
#pragma unroll
    for (int i = 0; i < CPG; ++i) pd[i] += __shfl_xor(pd[i], m);
  }
#pragma unroll
  for (int m = 1; m < 64; m <<= 1) sq += __shfl_xor(sq, m);
  if (lane == 0) sqred[wv] = sq;

  __syncthreads();   // the ONE barrier: mask partials + sqred visible

  // ---- assemble full mask, exponentiate ----
  float4 Ms = make_float4(0.f, 0.f, 0.f, 0.f);
  float4 Mt = make_float4(0.f, 0.f, 0.f, 0.f);
#pragma unroll
  for (int w = 0; w < 8; ++w) {
    const float4 a = mredw[0][w][nq];
    Ms.x += a.x; Ms.y += a.y; Ms.z += a.z; Ms.w += a.w;
    const float4 c = mredw[1][w][nq];
    Mt.x += c.x; Mt.y += c.y; Mt.z += c.z; Mt.w += c.w;
  }
  float4 es, et;
  es.x = __expf(Ms.x + bS); es.y = __expf(Ms.y + bS);
  es.z = __expf(Ms.z + bS); es.w = __expf(Ms.w + bS);
  et.x = __expf(Mt.x + bT); et.y = __expf(Mt.y + bT);
  et.z = __expf(Mt.z + bT); et.w = __expf(Mt.w + bT);

  // ---- weighted-sum partials + denominators, all in-register ----
  float dens = es.x + es.y + es.z + es.w;
  float dent = et.x + et.y + et.z + et.w;
  float ps[CPG], pt[CPG];
#pragma unroll
  for (int i = 0; i < CPG; ++i) {
    ps[i] = s4[i].x * es.x + s4[i].y * es.y + s4[i].z * es.z + s4[i].w * es.w;
    pt[i] = t4[i].x * et.x + t4[i].y * et.y + t4[i].z * et.z + t4[i].w * et.w;
  }
#pragma unroll
  for (int m = 1; m <= 8; m <<= 1) {
#pragma unroll
    for (int i = 0; i < CPG; ++i) {
      ps[i] += __shfl_xor(ps[i], m);
      pt[i] += __shfl_xor(pt[i], m);
    }
    dens += __shfl_xor(dens, m);
    dent += __shfl_xor(dent, m);
  }

  // ---- lane -> channel pick (static select chain) + slotted atomics ----
  const int k = sub & 7;
  float vs = ps[0], vt = pt[0], vd = pd[0];
#pragma unroll
  for (int i = 1; i < CPG; ++i) {
    const bool m = (k == i);
    vs = m ? ps[i] : vs;
    vt = m ? pt[i] : vt;
    vd = m ? pd[i] : vd;
  }

  if (sub < 8) {
    atomicAdd(&ctxnum[(((size_t)slot * 2 + 0) * Bc + b) * Cc + c0 + k], vs);
    atomicAdd(&rowsum[((size_t)slot * Bc + b) * Cc + c0 + k], vd);
  } else {
    atomicAdd(&ctxnum[(((size_t)slot * 2 + 1) * Bc + b) * Cc + c0 + k], vt);
  }
  if (tid == 0) {
    atomicAdd(&den[slot * 4 + 0 * Bc + b], dens);
    atomicAdd(&den[slot * 4 + 1 * Bc + b], dent);
  }
  if (tid == 64) {   // wave 1 lane 0: sqred complete since the barrier
    float v = 0.f;
#pragma unroll
    for (int w = 0; w < 8; ++w) v += sqred[w];
    atomicAdd(&sumsq[slot], v);
  }
}

// ---------------------------------------------------------------------------
// K4a: channel_add MLP per (tt,b). grid 4, block 1024. ctx = fold NSLOT slots
// of ctxnum / den at load time. float4 weight loads.
// ---------------------------------------------------------------------------
__global__ __launch_bounds__(1024) void gc_k4a_mlp(
    const float* __restrict__ ctxr, const float* __restrict__ den,
    const float* __restrict__ w1s, const float* __restrict__ b1s,
    const float* __restrict__ gs,  const float* __restrict__ bes,
    const float* __restrict__ w2s, const float* __restrict__ b2s,
    const float* __restrict__ w1t, const float* __restrict__ b1t,
    const float* __restrict__ gt,  const float* __restrict__ bet,
    const float* __restrict__ w2t, const float* __restrict__ b2t,
    float* __restrict__ addv) {
  const int tt  = blockIdx.x >> 1;
  const int b   = blockIdx.x & 1;
  const int tid = threadIdx.x;

  const float* w1 = tt ? w1t : w1s;
  const float* b1 = tt ? b1t : b1s;
  const float* g  = tt ? gt  : gs;
  const float* be = tt ? bet : bes;
  const float* w2 = tt ? w2t : w2s;
  const float* b2 = tt ? b2t : b2s;

  __shared__ float cxs[Cc];
  __shared__ float part[1024];
  __shared__ float hbuf[CHc];
  __shared__ float hr[CHc];
  __shared__ float2 red2[128];
  __shared__ float mu_s, rstd_s;

  if (tid < Cc) {
    float num = 0.f, dn = 0.f;
#pragma unroll
    for (int kk = 0; kk < NSLOT; ++kk) {
      num += ctxr[(((size_t)kk * 2 + tt) * Bc + b) * Cc + tid];
      dn  += den[kk * 4 + tt * Bc + b];
    }
    cxs[tid] = num / dn;
  }
  __syncthreads();

  // stage 1: h[j] = sum_c ctx[c]*w1[j][c] + b1[j]   (128 j x 8 segments)
  {
    const int j = tid >> 3, s = tid & 7;
    const float* wr = w1 + j * Cc + s * 32;
    const float4* cx4 = (const float4*)(cxs + s * 32);
    float acc = 0.f;
#pragma unroll
    for (int kk = 0; kk < 8; ++kk) {
      const float4 w = *(const float4*)(wr + kk * 4);
      const float4 x = cx4[kk];
      acc += w.x * x.x + w.y * x.y + w.z * x.z + w.w * x.w;
    }
    part[tid] = acc;
  }
  __syncthreads();
  if (tid < CHc) {
    float h = b1[tid];
#pragma unroll
    for (int q = 0; q < 8; ++q) h += part[tid * 8 + q];
    hbuf[tid] = h;
  }
  __syncthreads();

  // LN stats over 128
  if (tid < CHc) {
    const float v = hbuf[tid];
    red2[tid] = make_float2(v, v * v);
  }
  __syncthreads();
  for (int s = 64; s > 0; s >>= 1) {
    if (tid < s) {
      red2[tid].x += red2[tid + s].x;
      red2[tid].y += red2[tid + s].y;
    }
    __syncthreads();
  }
  if (tid == 0) {
    const float mu = red2[0].x / (float)CHc;
    const float var = red2[0].y / (float)CHc - mu * mu;
    mu_s = mu;
    rstd_s = rsqrtf(var + LN_EPS);
  }
  __syncthreads();
  if (tid < CHc) {
    const float v = (hbuf[tid] - mu_s) * rstd_s * g[tid] + be[tid];
    hr[tid] = v > 0.f ? v : 0.f;
  }
  __syncthreads();

  // stage 3: addv[c] = sum_j hr[j]*w2[c][j] + b2[c]   (256 c x 4 segments)
  {
    const int c = tid >> 2, q = tid & 3;
    const float* wr = w2 + c * CHc + q * 32;
    const float4* h4 = (const float4*)(hr + q * 32);
    float acc = 0.f;
#pragma unroll
    for (int kk = 0; kk < 8; ++kk) {
      const float4 w = *(const float4*)(wr + kk * 4);
      const float4 x = h4[kk];
      acc += w.x * x.x + w.y * x.y + w.z * x.z + w.w * x.w;
    }
    part[tid] = acc;
  }
  __syncthreads();
  if (tid < Cc) {
    float acc = b2[tid];
#pragma unroll
    for (int q = 0; q < 4; ++q) acc += part[tid * 4 + q];
    addv[((size_t)tt * Bc + b) * Cc + tid] = acc;
  }
}

// ---------------------------------------------------------------------------
// K4b: final scalar. 1 block, 256 thr. Folds the NSLOT rowsum/sumsq slots.
// out = (sumsq + sum_{b,c} [2*delta*rowsum + N*delta^2]) / B
// ---------------------------------------------------------------------------
__global__ __launch_bounds__(256) void gc_k4b_final(
    const float* __restrict__ addv, const float* __restrict__ rowsum,
    const float* __restrict__ sumsq, float* __restrict__ out) {
  const int tid = threadIdx.x;
  __shared__ float red[256];
  float part = 0.f;
  for (int job = tid; job < Bc * Cc; job += 256) {
    const int c = job & (Cc - 1);
    const int b = job >> 8;
    const float delta = addv[((size_t)0 * Bc + b) * Cc + c] -
                        addv[((size_t)1 * Bc + b) * Cc + c];
    float rs = 0.f;
#pragma unroll
    for (int k = 0; k < NSLOT; ++k)
      rs += rowsum[((size_t)k * Bc + b) * Cc + c];
    part += 2.f * delta * rs + (float)Nn * delta * delta;
  }
  red[tid] = part;
  __syncthreads();
  for (int s = 128; s > 0; s >>= 1) {
    if (tid < s) red[tid] += red[tid + s];
    __syncthreads();
  }
  if (tid == 0) {
    float sq = 0.f;
#pragma unroll
    for (int k = 0; k < NSLOT; ++k) sq += sumsq[k];
    out[0] = (red[0] + sq) / (float)Bc;
  }
}

// ---------------------------------------------------------------------------
extern "C" void kernel_launch(void* const* d_in, const int* in_sizes, int n_in,
                              void* d_out, int out_size, void* d_ws,
                              size_t ws_size, hipStream_t stream) {
  const float* S   = (const float*)d_in[0];
  const float* T   = (const float*)d_in[1];
  const float* wms = (const float*)d_in[2];
  const float* bms = (const float*)d_in[3];
  const float* wmt = (const float*)d_in[4];
  const float* bmt = (const float*)d_in[5];
  const float* w1s = (const float*)d_in[6];
  const float* b1s = (const float*)d_in[7];
  const float* gs  = (const float*)d_in[8];
  const float* bes = (const float*)d_in[9];
  const float* w2s = (const float*)d_in[10];
  const float* b2s = (const float*)d_in[11];
  const float* w1t = (const float*)d_in[12];
  const float* b1t = (const float*)d_in[13];
  const float* gt  = (const float*)d_in[14];
  const float* bet = (const float*)d_in[15];
  const float* w2t = (const float*)d_in[16];
  const float* b2t = (const float*)d_in[17];
  float* out = (float*)d_out;

  // ws layout (floats) — slotted accumulators first; one memset zeroes all.
  float* ws     = (float*)d_ws;
  float* ctxnum = ws;                               // NSLOT*2*B*C = 32768
  float* rowsum = ctxnum + NSLOT * 2 * Bc * Cc;     // NSLOT*B*C   = 16384
  float* den    = rowsum + NSLOT * Bc * Cc;         // NSLOT*4     = 128
  float* sumsq  = den + NSLOT * 4;                  // NSLOT       = 32
  float* addv   = sumsq + NSLOT;                    // 2*B*C       = 1024

  hipMemsetAsync(d_ws, 0,
                 (NSLOT * (2 * Bc * Cc + Bc * Cc + 4 + 1)) * sizeof(float),
                 stream);

  gc_fused<<<dim3(GRIDX, Bc), TPB, 0, stream>>>(S, T, wms, bms, wmt, bmt,
                                                ctxnum, rowsum, den, sumsq);
  gc_k4a_mlp<<<4, 1024, 0, stream>>>(ctxnum, den, w1s, b1s, gs, bes, w2s, b2s,
                                     w1t, b1t, gt, bet, w2t, b2t, addv);
  gc_k4b_final<<<1, 256, 0, stream>>>(addv, rowsum, sumsq, out);
}